// Round 1
// baseline (849.489 us; speedup 1.0000x reference)
//
#include <hip/hip_runtime.h>

#define NT 256

// ---------------------------------------------------------------------------
// Kernels
// ---------------------------------------------------------------------------

__global__ __launch_bounds__(NT) void degree_kernel(const int* __restrict__ src,
                                                    const int* __restrict__ dst,
                                                    int* __restrict__ cnt_out,
                                                    int* __restrict__ cnt_in, int e) {
    int t = blockIdx.x * NT + threadIdx.x;
    if (t < e) {
        atomicAdd(&cnt_out[src[t]], 1);
        atomicAdd(&cnt_in[dst[t]], 1);
    }
}

__global__ __launch_bounds__(NT) void norm_kernel(const int* __restrict__ cnt_out,
                                                  const int* __restrict__ cnt_in,
                                                  float* __restrict__ norm_src,
                                                  float* __restrict__ norm_dst, int n) {
    int t = blockIdx.x * NT + threadIdx.x;
    if (t < n) {
        int co = cnt_out[t]; if (co < 1) co = 1;
        int ci = cnt_in[t];  if (ci < 1) ci = 1;
        norm_src[t] = 1.0f / sqrtf((float)co);
        norm_dst[t] = 1.0f / sqrtf((float)ci);
    }
}

// ---- exclusive scan of cnt_in (3 kernels) ----
__global__ __launch_bounds__(1024) void scan_block(const int* __restrict__ cnt,
                                                   int* __restrict__ excl,
                                                   int* __restrict__ partials, int n) {
    __shared__ int tmp[1024];
    int tid = threadIdx.x;
    int gid = blockIdx.x * 1024 + tid;
    int v = (gid < n) ? cnt[gid] : 0;
    int val = v;
    tmp[tid] = val;
    __syncthreads();
    for (int off = 1; off < 1024; off <<= 1) {
        int a = (tid >= off) ? tmp[tid - off] : 0;
        __syncthreads();
        val += a;
        tmp[tid] = val;
        __syncthreads();
    }
    if (gid < n) excl[gid] = val - v;     // exclusive
    if (tid == 1023) partials[blockIdx.x] = val;  // block total (inclusive of last)
}

__global__ void scan_partials(int* partials, int nb) {
    if (threadIdx.x == 0 && blockIdx.x == 0) {
        int run = 0;
        for (int i = 0; i < nb; i++) { int v = partials[i]; partials[i] = run; run += v; }
    }
}

__global__ __launch_bounds__(NT) void scan_add(int* __restrict__ rowoff,
                                               const int* __restrict__ partials,
                                               int* __restrict__ cursor, int n) {
    int t = blockIdx.x * NT + threadIdx.x;
    if (t < n) {
        int o = rowoff[t] + partials[t >> 10];
        rowoff[t] = o;
        cursor[t] = o;
    }
}

__global__ __launch_bounds__(NT) void fill_kernel(const int* __restrict__ src,
                                                  const int* __restrict__ dst,
                                                  int* __restrict__ cursor,
                                                  int* __restrict__ esrc, int e) {
    int t = blockIdx.x * NT + threadIdx.x;
    if (t < e) {
        int d = dst[t];
        int p = atomicAdd(&cursor[d], 1);
        esrc[p] = src[t];
    }
}

// ---- GEMM1: y1[i][0..15] = (x[i] @ W1) * norm_src[i] ----
#define GROWS 256
#define BK 32
__global__ __launch_bounds__(NT) void gemm1_kernel(const float* __restrict__ x,
                                                   const float* __restrict__ W1,
                                                   const float* __restrict__ norm_src,
                                                   float* __restrict__ y1, int n) {
    __shared__ float xs[GROWS][BK + 1];  // pad 33 -> bank (r+k)%32, conflict-free
    int tid = threadIdx.x;
    int row0 = blockIdx.x * GROWS;
    int myrow = row0 + tid;

    float acc[16];
#pragma unroll
    for (int j = 0; j < 16; j++) acc[j] = 0.f;

    for (int kc = 0; kc < 512; kc += BK) {
        __syncthreads();
        // stage 256 rows x 32 floats = 2048 float4, 8 per thread, coalesced
#pragma unroll
        for (int i = 0; i < 8; i++) {
            int idx = tid + i * NT;
            int r = idx >> 3;
            int c4 = idx & 7;
            int grow = row0 + r;
            float4 v = make_float4(0.f, 0.f, 0.f, 0.f);
            if (grow < n) v = *(const float4*)&x[(size_t)grow * 512 + kc + c4 * 4];
            float* dp = &xs[r][c4 * 4];
            dp[0] = v.x; dp[1] = v.y; dp[2] = v.z; dp[3] = v.w;
        }
        __syncthreads();
#pragma unroll 4
        for (int kk = 0; kk < BK; kk++) {
            float xv = xs[tid][kk];
            const float4 w0 = *(const float4*)&W1[(kc + kk) * 16 + 0];
            const float4 w1 = *(const float4*)&W1[(kc + kk) * 16 + 4];
            const float4 w2 = *(const float4*)&W1[(kc + kk) * 16 + 8];
            const float4 w3 = *(const float4*)&W1[(kc + kk) * 16 + 12];
            acc[0]  += xv * w0.x; acc[1]  += xv * w0.y; acc[2]  += xv * w0.z; acc[3]  += xv * w0.w;
            acc[4]  += xv * w1.x; acc[5]  += xv * w1.y; acc[6]  += xv * w1.z; acc[7]  += xv * w1.w;
            acc[8]  += xv * w2.x; acc[9]  += xv * w2.y; acc[10] += xv * w2.z; acc[11] += xv * w2.w;
            acc[12] += xv * w3.x; acc[13] += xv * w3.y; acc[14] += xv * w3.z; acc[15] += xv * w3.w;
        }
    }

    if (myrow < n) {
        float ns = norm_src[myrow];
        float4* op = (float4*)&y1[(size_t)myrow * 16];
        op[0] = make_float4(acc[0] * ns,  acc[1] * ns,  acc[2] * ns,  acc[3] * ns);
        op[1] = make_float4(acc[4] * ns,  acc[5] * ns,  acc[6] * ns,  acc[7] * ns);
        op[2] = make_float4(acc[8] * ns,  acc[9] * ns,  acc[10] * ns, acc[11] * ns);
        op[3] = make_float4(acc[12] * ns, acc[13] * ns, acc[14] * ns, acc[15] * ns);
    }
}

// ---- CSR aggregation: agg[d][j] = sum over in-edges of feat[src][j]; 16 lanes/node ----
__global__ __launch_bounds__(NT) void aggregate16(const float* __restrict__ feat,
                                                  const int* __restrict__ rowoff,
                                                  const int* __restrict__ esrc,
                                                  float* __restrict__ agg, int n, int e) {
    int tid = threadIdx.x;
    int d = blockIdx.x * 16 + (tid >> 4);
    int j = tid & 15;
    if (d >= n) return;
    int beg = rowoff[d];
    int end = (d + 1 < n) ? rowoff[d + 1] : e;
    float acc = 0.f;
    for (int p = beg; p < end; ++p) {
        int s = esrc[p];
        acc += feat[(size_t)s * 16 + j];
    }
    agg[(size_t)d * 16 + j] = acc;
}

// ---- h1s = relu(agg1*norm_dst + b1) * norm_src ----
__global__ __launch_bounds__(NT) void act_kernel(const float* __restrict__ agg,
                                                 const float* __restrict__ norm_dst,
                                                 const float* __restrict__ norm_src,
                                                 const float* __restrict__ b1,
                                                 float* __restrict__ h1s, int n) {
    int t = blockIdx.x * NT + threadIdx.x;  // one float4 per thread
    if (t >= n * 4) return;
    int i = t >> 2, q = t & 3;
    float nd = norm_dst[i], ns = norm_src[i];
    float4 a = *(const float4*)&agg[(size_t)i * 16 + q * 4];
    float4 bb = *(const float4*)&b1[q * 4];
    float4 r;
    r.x = fmaxf(a.x * nd + bb.x, 0.f) * ns;
    r.y = fmaxf(a.y * nd + bb.y, 0.f) * ns;
    r.z = fmaxf(a.z * nd + bb.z, 0.f) * ns;
    r.w = fmaxf(a.w * nd + bb.w, 0.f) * ns;
    *(float4*)&h1s[(size_t)i * 16 + q * 4] = r;
}

// ---- out[i][j] = (agg2[i] @ W2)[j] * norm_dst[i] + b2[j] ----
__global__ __launch_bounds__(NT) void final_kernel(const float* __restrict__ agg,
                                                   const float* __restrict__ W2,
                                                   const float* __restrict__ b2,
                                                   const float* __restrict__ norm_dst,
                                                   float* __restrict__ out, int n) {
    __shared__ float sW[16 * 64];
    __shared__ float sA[4][16];
    int tid = threadIdx.x;
    *(float4*)&sW[tid * 4] = *(const float4*)&W2[tid * 4];  // 1024 floats
    int i0 = blockIdx.x * 4;
    if (tid < 64) {
        int r = tid >> 4, k = tid & 15;
        int gi = i0 + r;
        sA[r][k] = (gi < n) ? agg[(size_t)gi * 16 + k] : 0.f;
    }
    __syncthreads();
    int r = tid >> 6, j = tid & 63;
    int gi = i0 + r;
    if (gi >= n) return;
    float acc = 0.f;
#pragma unroll
    for (int k = 0; k < 16; k++) acc += sA[r][k] * sW[k * 64 + j];
    out[(size_t)gi * 64 + j] = acc * norm_dst[gi] + b2[j];
}

// ---------------------------------------------------------------------------
// Launch
// ---------------------------------------------------------------------------
extern "C" void kernel_launch(void* const* d_in, const int* in_sizes, int n_in,
                              void* d_out, int out_size, void* d_ws, size_t ws_size,
                              hipStream_t stream) {
    const float* x  = (const float*)d_in[0];
    const float* W1 = (const float*)d_in[1];
    const float* b1 = (const float*)d_in[2];
    const float* W2 = (const float*)d_in[3];
    const float* b2 = (const float*)d_in[4];
    const int* src  = (const int*)d_in[5];
    const int* dst  = (const int*)d_in[6];

    int n = in_sizes[0] / 512;   // 100000
    int e = in_sizes[5];         // 3200000
    float* out = (float*)d_out;

    char* ws = (char*)d_ws;
    size_t off = 0;
    auto alloc = [&](size_t bytes) { size_t o = off; off = (off + bytes + 255) & ~(size_t)255; return o; };
    int*   cnt_out  = (int*)(ws + alloc((size_t)n * 4));
    int*   cnt_in   = (int*)(ws + alloc((size_t)n * 4));
    size_t norm_off = off;
    float* norm_src = (float*)(ws + alloc((size_t)n * 4));
    float* norm_dst = (float*)(ws + alloc((size_t)n * 4));
    int*   rowoff   = (int*)(ws + alloc((size_t)n * 4));
    int*   cursor   = (int*)(ws + alloc((size_t)n * 4));
    int*   partials = (int*)(ws + alloc(512));
    int*   esrc     = (int*)(ws + alloc((size_t)e * 4));
    float* bufA     = (float*)(ws + alloc((size_t)n * 16 * 4));  // y1, then h1s
    float* bufAgg   = (float*)(ws + alloc((size_t)n * 16 * 4));  // agg1, then agg2
    if (off > ws_size) return;  // workspace insufficient -> will show as absmax fail

    int eb = (e + NT - 1) / NT;
    int nb = (n + NT - 1) / NT;
    int sb = (n + 1023) / 1024;  // scan blocks (98)

    // zero the degree counters (covers both arrays incl. alignment padding)
    hipMemsetAsync(ws, 0, norm_off, stream);

    degree_kernel<<<eb, NT, 0, stream>>>(src, dst, cnt_out, cnt_in, e);
    norm_kernel<<<nb, NT, 0, stream>>>(cnt_out, cnt_in, norm_src, norm_dst, n);

    scan_block<<<sb, 1024, 0, stream>>>(cnt_in, rowoff, partials, n);
    scan_partials<<<1, 64, 0, stream>>>(partials, sb);
    scan_add<<<nb, NT, 0, stream>>>(rowoff, partials, cursor, n);
    fill_kernel<<<eb, NT, 0, stream>>>(src, dst, cursor, esrc, e);

    gemm1_kernel<<<(n + GROWS - 1) / GROWS, NT, 0, stream>>>(x, W1, norm_src, bufA, n);
    aggregate16<<<(n + 15) / 16, NT, 0, stream>>>(bufA, rowoff, esrc, bufAgg, n, e);
    act_kernel<<<((n * 4) + NT - 1) / NT, NT, 0, stream>>>(bufAgg, norm_dst, norm_src, b1, bufA, n);
    aggregate16<<<(n + 15) / 16, NT, 0, stream>>>(bufA, rowoff, esrc, bufAgg, n, e);
    final_kernel<<<(n + 3) / 4, NT, 0, stream>>>(bufAgg, W2, b2, norm_dst, out, n);
}

// Round 2
// 444.746 us; speedup vs baseline: 1.9101x; 1.9101x over previous
//
#include <hip/hip_runtime.h>

#define NT 256
#define EPB 8192       // edges per block for bucket passes
#define MAXBKT 512     // static LDS sizing; nbkt = ceil(n/256) = 391 for n=100000

// ---------------------------------------------------------------------------
// Pass A: histogram edges into dst-buckets and src-buckets (bucket = id >> 8)
// ---------------------------------------------------------------------------
__global__ __launch_bounds__(NT) void bucket_count(const int* __restrict__ src,
                                                   const int* __restrict__ dst,
                                                   int* __restrict__ cntD,
                                                   int* __restrict__ cntS, int e, int nbkt) {
    __shared__ int hD[MAXBKT], hS[MAXBKT];
    int tid = threadIdx.x;
    for (int i = tid; i < nbkt; i += NT) { hD[i] = 0; hS[i] = 0; }
    __syncthreads();
    int p0 = blockIdx.x * EPB;
    int pend = min(p0 + EPB, e);
    for (int p = p0 + tid; p < pend; p += NT) {
        atomicAdd(&hD[dst[p] >> 8], 1);
        atomicAdd(&hS[src[p] >> 8], 1);
    }
    __syncthreads();
    for (int i = tid; i < nbkt; i += NT) {
        if (hD[i]) atomicAdd(&cntD[i], hD[i]);
        if (hS[i]) atomicAdd(&cntS[i], hS[i]);
    }
}

// ---------------------------------------------------------------------------
// Pass B: exclusive scan of bucket counts (nbkt <= 512, one block)
// ---------------------------------------------------------------------------
__global__ __launch_bounds__(512) void bucket_scan(const int* __restrict__ cntD,
                                                   const int* __restrict__ cntS,
                                                   int* __restrict__ bkoD,
                                                   int* __restrict__ bkoS,
                                                   int* __restrict__ gcurD,
                                                   int* __restrict__ gcurS, int e, int nbkt) {
    __shared__ int tD[512], tS[512];
    int tid = threadIdx.x;
    int vD = (tid < nbkt) ? cntD[tid] : 0;
    int vS = (tid < nbkt) ? cntS[tid] : 0;
    int valD = vD, valS = vS;
    tD[tid] = valD; tS[tid] = valS;
    __syncthreads();
    for (int off = 1; off < 512; off <<= 1) {
        int aD = (tid >= off) ? tD[tid - off] : 0;
        int aS = (tid >= off) ? tS[tid - off] : 0;
        __syncthreads();
        valD += aD; valS += aS;
        tD[tid] = valD; tS[tid] = valS;
        __syncthreads();
    }
    if (tid < nbkt) {
        int oD = valD - vD, oS = valS - vS;
        bkoD[tid] = oD; bkoS[tid] = oS;
        gcurD[tid] = oD; gcurS[tid] = oS;
    }
    if (tid == 0) { bkoD[nbkt] = e; bkoS[nbkt] = e; }
}

// ---------------------------------------------------------------------------
// Pass C: scatter edges into bucket regions (block-local LDS bucketing)
//   ebinD[slot] = src | (dst&255)<<17   (src < 2^17, n=100000)
//   ebinS[slot] = src
// ---------------------------------------------------------------------------
__global__ __launch_bounds__(NT) void bucket_scatter(const int* __restrict__ src,
                                                     const int* __restrict__ dst,
                                                     int* __restrict__ gcurD,
                                                     int* __restrict__ gcurS,
                                                     unsigned int* __restrict__ ebinD,
                                                     int* __restrict__ ebinS, int e, int nbkt) {
    __shared__ int hD[MAXBKT], hS[MAXBKT];
    __shared__ int cD[MAXBKT], cS[MAXBKT];
    int tid = threadIdx.x;
    for (int i = tid; i < nbkt; i += NT) { hD[i] = 0; hS[i] = 0; }
    __syncthreads();
    int p0 = blockIdx.x * EPB;
    int pend = min(p0 + EPB, e);
    for (int p = p0 + tid; p < pend; p += NT) {
        atomicAdd(&hD[dst[p] >> 8], 1);
        atomicAdd(&hS[src[p] >> 8], 1);
    }
    __syncthreads();
    for (int i = tid; i < nbkt; i += NT) {
        cD[i] = hD[i] ? atomicAdd(&gcurD[i], hD[i]) : 0;
        cS[i] = hS[i] ? atomicAdd(&gcurS[i], hS[i]) : 0;
    }
    __syncthreads();
    for (int p = p0 + tid; p < pend; p += NT) {
        int s = src[p], d = dst[p];
        int slotD = atomicAdd(&cD[d >> 8], 1);
        ebinD[slotD] = (unsigned int)s | ((unsigned int)(d & 255) << 17);
        int slotS = atomicAdd(&cS[s >> 8], 1);
        ebinS[slotS] = s;
    }
}

// ---------------------------------------------------------------------------
// Pass D_s: per-bucket out-degree histogram -> norm_src
// ---------------------------------------------------------------------------
__global__ __launch_bounds__(NT) void src_degree(const int* __restrict__ ebinS,
                                                 const int* __restrict__ bkoS,
                                                 float* __restrict__ norm_src, int n) {
    __shared__ int cnt[256];
    int b = blockIdx.x, tid = threadIdx.x;
    cnt[tid] = 0;
    __syncthreads();
    int p0 = bkoS[b], p1 = bkoS[b + 1];
    for (int p = p0 + tid; p < p1; p += NT) atomicAdd(&cnt[ebinS[p] & 255], 1);
    __syncthreads();
    int node = (b << 8) + tid;
    if (node < n) norm_src[node] = rsqrtf((float)max(cnt[tid], 1));
}

// ---------------------------------------------------------------------------
// Pass D_d: per-bucket in-degree histogram + LDS scan -> rowoff, norm_dst,
//           then fill esrc within the bucket's contiguous edge region
// ---------------------------------------------------------------------------
__global__ __launch_bounds__(NT) void dst_fill(const unsigned int* __restrict__ ebinD,
                                               const int* __restrict__ bkoD,
                                               int* __restrict__ rowoff,
                                               float* __restrict__ norm_dst,
                                               int* __restrict__ esrc, int n) {
    __shared__ int cnt[256], cur[256], tmp[256];
    int b = blockIdx.x, tid = threadIdx.x;
    cnt[tid] = 0;
    __syncthreads();
    int p0 = bkoD[b], p1 = bkoD[b + 1];
    for (int p = p0 + tid; p < p1; p += NT) atomicAdd(&cnt[ebinD[p] >> 17], 1);
    __syncthreads();
    int v = cnt[tid];
    int val = v;
    tmp[tid] = val;
    __syncthreads();
    for (int off = 1; off < 256; off <<= 1) {
        int a = (tid >= off) ? tmp[tid - off] : 0;
        __syncthreads();
        val += a;
        tmp[tid] = val;
        __syncthreads();
    }
    int excl = val - v;
    int node = (b << 8) + tid;
    if (node < n) {
        rowoff[node] = p0 + excl;
        norm_dst[node] = rsqrtf((float)max(v, 1));
    }
    cur[tid] = p0 + excl;
    __syncthreads();
    for (int p = p0 + tid; p < p1; p += NT) {
        unsigned int w = ebinD[p];
        int pos = atomicAdd(&cur[w >> 17], 1);
        esrc[pos] = (int)(w & 0x1FFFFu);
    }
}

// ---- GEMM1: y1[i][0..15] = (x[i] @ W1) * norm_src[i] ----
#define GROWS 256
#define BK 32
__global__ __launch_bounds__(NT) void gemm1_kernel(const float* __restrict__ x,
                                                   const float* __restrict__ W1,
                                                   const float* __restrict__ norm_src,
                                                   float* __restrict__ y1, int n) {
    __shared__ float xs[GROWS][BK + 1];
    int tid = threadIdx.x;
    int row0 = blockIdx.x * GROWS;
    int myrow = row0 + tid;

    float acc[16];
#pragma unroll
    for (int j = 0; j < 16; j++) acc[j] = 0.f;

    for (int kc = 0; kc < 512; kc += BK) {
        __syncthreads();
#pragma unroll
        for (int i = 0; i < 8; i++) {
            int idx = tid + i * NT;
            int r = idx >> 3;
            int c4 = idx & 7;
            int grow = row0 + r;
            float4 v = make_float4(0.f, 0.f, 0.f, 0.f);
            if (grow < n) v = *(const float4*)&x[(size_t)grow * 512 + kc + c4 * 4];
            float* dp = &xs[r][c4 * 4];
            dp[0] = v.x; dp[1] = v.y; dp[2] = v.z; dp[3] = v.w;
        }
        __syncthreads();
#pragma unroll 4
        for (int kk = 0; kk < BK; kk++) {
            float xv = xs[tid][kk];
            const float4 w0 = *(const float4*)&W1[(kc + kk) * 16 + 0];
            const float4 w1 = *(const float4*)&W1[(kc + kk) * 16 + 4];
            const float4 w2 = *(const float4*)&W1[(kc + kk) * 16 + 8];
            const float4 w3 = *(const float4*)&W1[(kc + kk) * 16 + 12];
            acc[0]  += xv * w0.x; acc[1]  += xv * w0.y; acc[2]  += xv * w0.z; acc[3]  += xv * w0.w;
            acc[4]  += xv * w1.x; acc[5]  += xv * w1.y; acc[6]  += xv * w1.z; acc[7]  += xv * w1.w;
            acc[8]  += xv * w2.x; acc[9]  += xv * w2.y; acc[10] += xv * w2.z; acc[11] += xv * w2.w;
            acc[12] += xv * w3.x; acc[13] += xv * w3.y; acc[14] += xv * w3.z; acc[15] += xv * w3.w;
        }
    }

    if (myrow < n) {
        float ns = norm_src[myrow];
        float4* op = (float4*)&y1[(size_t)myrow * 16];
        op[0] = make_float4(acc[0] * ns,  acc[1] * ns,  acc[2] * ns,  acc[3] * ns);
        op[1] = make_float4(acc[4] * ns,  acc[5] * ns,  acc[6] * ns,  acc[7] * ns);
        op[2] = make_float4(acc[8] * ns,  acc[9] * ns,  acc[10] * ns, acc[11] * ns);
        op[3] = make_float4(acc[12] * ns, acc[13] * ns, acc[14] * ns, acc[15] * ns);
    }
}

// ---- CSR aggregation: 16 lanes per node ----
__global__ __launch_bounds__(NT) void aggregate16(const float* __restrict__ feat,
                                                  const int* __restrict__ rowoff,
                                                  const int* __restrict__ esrc,
                                                  float* __restrict__ agg, int n, int e) {
    int tid = threadIdx.x;
    int d = blockIdx.x * 16 + (tid >> 4);
    int j = tid & 15;
    if (d >= n) return;
    int beg = rowoff[d];
    int end = (d + 1 < n) ? rowoff[d + 1] : e;
    float acc = 0.f;
    for (int p = beg; p < end; ++p) {
        int s = esrc[p];
        acc += feat[(size_t)s * 16 + j];
    }
    agg[(size_t)d * 16 + j] = acc;
}

// ---- h1s = relu(agg1*norm_dst + b1) * norm_src ----
__global__ __launch_bounds__(NT) void act_kernel(const float* __restrict__ agg,
                                                 const float* __restrict__ norm_dst,
                                                 const float* __restrict__ norm_src,
                                                 const float* __restrict__ b1,
                                                 float* __restrict__ h1s, int n) {
    int t = blockIdx.x * NT + threadIdx.x;
    if (t >= n * 4) return;
    int i = t >> 2, q = t & 3;
    float nd = norm_dst[i], ns = norm_src[i];
    float4 a = *(const float4*)&agg[(size_t)i * 16 + q * 4];
    float4 bb = *(const float4*)&b1[q * 4];
    float4 r;
    r.x = fmaxf(a.x * nd + bb.x, 0.f) * ns;
    r.y = fmaxf(a.y * nd + bb.y, 0.f) * ns;
    r.z = fmaxf(a.z * nd + bb.z, 0.f) * ns;
    r.w = fmaxf(a.w * nd + bb.w, 0.f) * ns;
    *(float4*)&h1s[(size_t)i * 16 + q * 4] = r;
}

// ---- out[i][j] = (agg2[i] @ W2)[j] * norm_dst[i] + b2[j] ----
__global__ __launch_bounds__(NT) void final_kernel(const float* __restrict__ agg,
                                                   const float* __restrict__ W2,
                                                   const float* __restrict__ b2,
                                                   const float* __restrict__ norm_dst,
                                                   float* __restrict__ out, int n) {
    __shared__ float sW[16 * 64];
    __shared__ float sA[4][16];
    int tid = threadIdx.x;
    *(float4*)&sW[tid * 4] = *(const float4*)&W2[tid * 4];
    int i0 = blockIdx.x * 4;
    if (tid < 64) {
        int r = tid >> 4, k = tid & 15;
        int gi = i0 + r;
        sA[r][k] = (gi < n) ? agg[(size_t)gi * 16 + k] : 0.f;
    }
    __syncthreads();
    int r = tid >> 6, j = tid & 63;
    int gi = i0 + r;
    if (gi >= n) return;
    float acc = 0.f;
#pragma unroll
    for (int k = 0; k < 16; k++) acc += sA[r][k] * sW[k * 64 + j];
    out[(size_t)gi * 64 + j] = acc * norm_dst[gi] + b2[j];
}

// ---------------------------------------------------------------------------
// Launch
// ---------------------------------------------------------------------------
extern "C" void kernel_launch(void* const* d_in, const int* in_sizes, int n_in,
                              void* d_out, int out_size, void* d_ws, size_t ws_size,
                              hipStream_t stream) {
    const float* x  = (const float*)d_in[0];
    const float* W1 = (const float*)d_in[1];
    const float* b1 = (const float*)d_in[2];
    const float* W2 = (const float*)d_in[3];
    const float* b2 = (const float*)d_in[4];
    const int* src  = (const int*)d_in[5];
    const int* dst  = (const int*)d_in[6];

    int n = in_sizes[0] / 512;   // 100000
    int e = in_sizes[5];         // 3200000
    float* out = (float*)d_out;

    int nbkt = (n + 255) >> 8;   // 391

    char* ws = (char*)d_ws;
    size_t off = 0;
    auto alloc = [&](size_t bytes) { size_t o = off; off = (off + bytes + 255) & ~(size_t)255; return o; };
    int*   cntD  = (int*)(ws + alloc(MAXBKT * 4));
    int*   cntS  = (int*)(ws + alloc(MAXBKT * 4));
    size_t zero_end = off;                       // memset region [0, zero_end)
    int*   bkoD  = (int*)(ws + alloc((MAXBKT + 1) * 4));
    int*   bkoS  = (int*)(ws + alloc((MAXBKT + 1) * 4));
    int*   gcurD = (int*)(ws + alloc(MAXBKT * 4));
    int*   gcurS = (int*)(ws + alloc(MAXBKT * 4));
    float* norm_src = (float*)(ws + alloc((size_t)n * 4));
    float* norm_dst = (float*)(ws + alloc((size_t)n * 4));
    int*   rowoff   = (int*)(ws + alloc((size_t)n * 4));
    unsigned int* ebinD = (unsigned int*)(ws + alloc((size_t)e * 4));
    int*   ebinS = (int*)(ws + alloc((size_t)e * 4));   // later reused as esrc
    float* bufA   = (float*)(ws + alloc((size_t)n * 16 * 4));
    float* bufAgg = (float*)(ws + alloc((size_t)n * 16 * 4));
    if (off > ws_size) return;
    int* esrc = ebinS;  // alias: ebinS fully consumed by src_degree before dst_fill writes esrc

    int ebb = (e + EPB - 1) / EPB;    // 391 blocks
    int nb4 = ((n * 4) + NT - 1) / NT;

    hipMemsetAsync(ws, 0, zero_end, stream);

    bucket_count  <<<ebb, NT, 0, stream>>>(src, dst, cntD, cntS, e, nbkt);
    bucket_scan   <<<1, 512, 0, stream>>>(cntD, cntS, bkoD, bkoS, gcurD, gcurS, e, nbkt);
    bucket_scatter<<<ebb, NT, 0, stream>>>(src, dst, gcurD, gcurS, ebinD, ebinS, e, nbkt);
    src_degree    <<<nbkt, NT, 0, stream>>>(ebinS, bkoS, norm_src, n);
    gemm1_kernel  <<<(n + GROWS - 1) / GROWS, NT, 0, stream>>>(x, W1, norm_src, bufA, n);
    dst_fill      <<<nbkt, NT, 0, stream>>>(ebinD, bkoD, rowoff, norm_dst, esrc, n);
    aggregate16   <<<(n + 15) / 16, NT, 0, stream>>>(bufA, rowoff, esrc, bufAgg, n, e);
    act_kernel    <<<nb4, NT, 0, stream>>>(bufAgg, norm_dst, norm_src, b1, bufA, n);
    aggregate16   <<<(n + 15) / 16, NT, 0, stream>>>(bufA, rowoff, esrc, bufAgg, n, e);
    final_kernel  <<<(n + 3) / 4, NT, 0, stream>>>(bufAgg, W2, b2, norm_dst, out, n);
}

// Round 3
// 413.888 us; speedup vs baseline: 2.0525x; 1.0746x over previous
//
#include <hip/hip_runtime.h>

#define NT 256
#define EPB 8192       // edges per block for bucket passes
#define MAXBKT 512     // static LDS sizing; nbkt = ceil(n/256) = 391 for n=100000
#define KS 4           // K-split factor for gemm1
#define KLEN 128       // 512 / KS

// ---------------------------------------------------------------------------
// Pass A: histogram edges into dst-buckets and src-buckets (bucket = id >> 8)
// ---------------------------------------------------------------------------
__global__ __launch_bounds__(NT) void bucket_count(const int* __restrict__ src,
                                                   const int* __restrict__ dst,
                                                   int* __restrict__ cntD,
                                                   int* __restrict__ cntS, int e, int nbkt) {
    __shared__ int hD[MAXBKT], hS[MAXBKT];
    int tid = threadIdx.x;
    for (int i = tid; i < nbkt; i += NT) { hD[i] = 0; hS[i] = 0; }
    __syncthreads();
    int p0 = blockIdx.x * EPB;
    int pend = min(p0 + EPB, e);
    for (int p = p0 + tid; p < pend; p += NT) {
        atomicAdd(&hD[dst[p] >> 8], 1);
        atomicAdd(&hS[src[p] >> 8], 1);
    }
    __syncthreads();
    for (int i = tid; i < nbkt; i += NT) {
        if (hD[i]) atomicAdd(&cntD[i], hD[i]);
        if (hS[i]) atomicAdd(&cntS[i], hS[i]);
    }
}

// ---------------------------------------------------------------------------
// Pass B: exclusive scan of bucket counts (nbkt <= 512, one block)
// ---------------------------------------------------------------------------
__global__ __launch_bounds__(512) void bucket_scan(const int* __restrict__ cntD,
                                                   const int* __restrict__ cntS,
                                                   int* __restrict__ bkoD,
                                                   int* __restrict__ bkoS,
                                                   int* __restrict__ gcurD,
                                                   int* __restrict__ gcurS, int e, int nbkt) {
    __shared__ int tD[512], tS[512];
    int tid = threadIdx.x;
    int vD = (tid < nbkt) ? cntD[tid] : 0;
    int vS = (tid < nbkt) ? cntS[tid] : 0;
    int valD = vD, valS = vS;
    tD[tid] = valD; tS[tid] = valS;
    __syncthreads();
    for (int off = 1; off < 512; off <<= 1) {
        int aD = (tid >= off) ? tD[tid - off] : 0;
        int aS = (tid >= off) ? tS[tid - off] : 0;
        __syncthreads();
        valD += aD; valS += aS;
        tD[tid] = valD; tS[tid] = valS;
        __syncthreads();
    }
    if (tid < nbkt) {
        int oD = valD - vD, oS = valS - vS;
        bkoD[tid] = oD; bkoS[tid] = oS;
        gcurD[tid] = oD; gcurS[tid] = oS;
    }
    if (tid == 0) { bkoD[nbkt] = e; bkoS[nbkt] = e; }
}

// ---------------------------------------------------------------------------
// Pass C: scatter edges into bucket regions (block-local LDS bucketing)
//   ebinD[slot] = src | (dst&255)<<17   (src < 2^17, n=100000)
//   ebinS8[slot] = src & 255            (bucket implied by slot position)
// ---------------------------------------------------------------------------
__global__ __launch_bounds__(NT) void bucket_scatter(const int* __restrict__ src,
                                                     const int* __restrict__ dst,
                                                     int* __restrict__ gcurD,
                                                     int* __restrict__ gcurS,
                                                     unsigned int* __restrict__ ebinD,
                                                     unsigned char* __restrict__ ebinS8,
                                                     int e, int nbkt) {
    __shared__ int hD[MAXBKT], hS[MAXBKT];
    __shared__ int cD[MAXBKT], cS[MAXBKT];
    int tid = threadIdx.x;
    for (int i = tid; i < nbkt; i += NT) { hD[i] = 0; hS[i] = 0; }
    __syncthreads();
    int p0 = blockIdx.x * EPB;
    int pend = min(p0 + EPB, e);
    for (int p = p0 + tid; p < pend; p += NT) {
        atomicAdd(&hD[dst[p] >> 8], 1);
        atomicAdd(&hS[src[p] >> 8], 1);
    }
    __syncthreads();
    for (int i = tid; i < nbkt; i += NT) {
        cD[i] = hD[i] ? atomicAdd(&gcurD[i], hD[i]) : 0;
        cS[i] = hS[i] ? atomicAdd(&gcurS[i], hS[i]) : 0;
    }
    __syncthreads();
    for (int p = p0 + tid; p < pend; p += NT) {
        int s = src[p], d = dst[p];
        int slotD = atomicAdd(&cD[d >> 8], 1);
        ebinD[slotD] = (unsigned int)s | ((unsigned int)(d & 255) << 17);
        int slotS = atomicAdd(&cS[s >> 8], 1);
        ebinS8[slotS] = (unsigned char)(s & 255);
    }
}

// ---------------------------------------------------------------------------
// Pass D_s: per-bucket out-degree histogram -> norm_src
// ---------------------------------------------------------------------------
__global__ __launch_bounds__(NT) void src_degree(const unsigned char* __restrict__ ebinS8,
                                                 const int* __restrict__ bkoS,
                                                 float* __restrict__ norm_src, int n) {
    __shared__ int cnt[256];
    int b = blockIdx.x, tid = threadIdx.x;
    cnt[tid] = 0;
    __syncthreads();
    int p0 = bkoS[b], p1 = bkoS[b + 1];
    for (int p = p0 + tid; p < p1; p += NT) atomicAdd(&cnt[ebinS8[p]], 1);
    __syncthreads();
    int node = (b << 8) + tid;
    if (node < n) norm_src[node] = rsqrtf((float)max(cnt[tid], 1));
}

// ---------------------------------------------------------------------------
// Pass D_d: per-bucket in-degree histogram + LDS scan -> rowoff, norm_dst,
//           then fill esrc within the bucket's contiguous edge region
// ---------------------------------------------------------------------------
__global__ __launch_bounds__(NT) void dst_fill(const unsigned int* __restrict__ ebinD,
                                               const int* __restrict__ bkoD,
                                               int* __restrict__ rowoff,
                                               float* __restrict__ norm_dst,
                                               int* __restrict__ esrc, int n) {
    __shared__ int cnt[256], cur[256], tmp[256];
    int b = blockIdx.x, tid = threadIdx.x;
    cnt[tid] = 0;
    __syncthreads();
    int p0 = bkoD[b], p1 = bkoD[b + 1];
    for (int p = p0 + tid; p < p1; p += NT) atomicAdd(&cnt[ebinD[p] >> 17], 1);
    __syncthreads();
    int v = cnt[tid];
    int val = v;
    tmp[tid] = val;
    __syncthreads();
    for (int off = 1; off < 256; off <<= 1) {
        int a = (tid >= off) ? tmp[tid - off] : 0;
        __syncthreads();
        val += a;
        tmp[tid] = val;
        __syncthreads();
    }
    int excl = val - v;
    int node = (b << 8) + tid;
    if (node < n) {
        rowoff[node] = p0 + excl;
        norm_dst[node] = rsqrtf((float)max(v, 1));
    }
    cur[tid] = p0 + excl;
    __syncthreads();
    for (int p = p0 + tid; p < p1; p += NT) {
        unsigned int w = ebinD[p];
        int pos = atomicAdd(&cur[w >> 17], 1);
        esrc[pos] = (int)(w & 0x1FFFFu);
    }
}

// ---- GEMM1 (K-split): partial[ks][i][0..15] = x[i][ks*128:(ks+1)*128] @ W1[...] ----
#define GROWS 256
#define BK 32
__global__ __launch_bounds__(NT) void gemm1_partial(const float* __restrict__ x,
                                                    const float* __restrict__ W1,
                                                    float* __restrict__ partial,
                                                    int n, int nrb) {
    __shared__ float xs[GROWS][BK + 1];
    int tid = threadIdx.x;
    int rowblk = blockIdx.x % nrb;
    int ks = blockIdx.x / nrb;
    int row0 = rowblk * GROWS;
    int myrow = row0 + tid;
    int kbase = ks * KLEN;

    float acc[16];
#pragma unroll
    for (int j = 0; j < 16; j++) acc[j] = 0.f;

    for (int kc = kbase; kc < kbase + KLEN; kc += BK) {
        __syncthreads();
#pragma unroll
        for (int i = 0; i < 8; i++) {
            int idx = tid + i * NT;
            int r = idx >> 3;
            int c4 = idx & 7;
            int grow = row0 + r;
            float4 v = make_float4(0.f, 0.f, 0.f, 0.f);
            if (grow < n) v = *(const float4*)&x[(size_t)grow * 512 + kc + c4 * 4];
            float* dp = &xs[r][c4 * 4];
            dp[0] = v.x; dp[1] = v.y; dp[2] = v.z; dp[3] = v.w;
        }
        __syncthreads();
#pragma unroll 4
        for (int kk = 0; kk < BK; kk++) {
            float xv = xs[tid][kk];
            const float4 w0 = *(const float4*)&W1[(kc + kk) * 16 + 0];
            const float4 w1 = *(const float4*)&W1[(kc + kk) * 16 + 4];
            const float4 w2 = *(const float4*)&W1[(kc + kk) * 16 + 8];
            const float4 w3 = *(const float4*)&W1[(kc + kk) * 16 + 12];
            acc[0]  += xv * w0.x; acc[1]  += xv * w0.y; acc[2]  += xv * w0.z; acc[3]  += xv * w0.w;
            acc[4]  += xv * w1.x; acc[5]  += xv * w1.y; acc[6]  += xv * w1.z; acc[7]  += xv * w1.w;
            acc[8]  += xv * w2.x; acc[9]  += xv * w2.y; acc[10] += xv * w2.z; acc[11] += xv * w2.w;
            acc[12] += xv * w3.x; acc[13] += xv * w3.y; acc[14] += xv * w3.z; acc[15] += xv * w3.w;
        }
    }

    if (myrow < n) {
        float4* op = (float4*)&partial[((size_t)ks * n + myrow) * 16];
        op[0] = make_float4(acc[0],  acc[1],  acc[2],  acc[3]);
        op[1] = make_float4(acc[4],  acc[5],  acc[6],  acc[7]);
        op[2] = make_float4(acc[8],  acc[9],  acc[10], acc[11]);
        op[3] = make_float4(acc[12], acc[13], acc[14], acc[15]);
    }
}

// ---- y1[i][j] = (sum_ks partial[ks][i][j]) * norm_src[i]  (fixed order) ----
__global__ __launch_bounds__(NT) void reduce_kernel(const float* __restrict__ partial,
                                                    const float* __restrict__ norm_src,
                                                    float* __restrict__ y1, int n) {
    int t = blockIdx.x * NT + threadIdx.x;
    if (t >= n * 4) return;
    int i = t >> 2, q = t & 3;
    size_t stride = (size_t)n * 16;
    size_t base = (size_t)i * 16 + q * 4;
    float4 a = *(const float4*)&partial[base];
#pragma unroll
    for (int ks = 1; ks < KS; ks++) {
        float4 b = *(const float4*)&partial[(size_t)ks * stride + base];
        a.x += b.x; a.y += b.y; a.z += b.z; a.w += b.w;
    }
    float ns = norm_src[i];
    a.x *= ns; a.y *= ns; a.z *= ns; a.w *= ns;
    *(float4*)&y1[base] = a;
}

// ---- CSR aggregation: 16 lanes per node ----
__global__ __launch_bounds__(NT) void aggregate16(const float* __restrict__ feat,
                                                  const int* __restrict__ rowoff,
                                                  const int* __restrict__ esrc,
                                                  float* __restrict__ agg, int n, int e) {
    int tid = threadIdx.x;
    int d = blockIdx.x * 16 + (tid >> 4);
    int j = tid & 15;
    if (d >= n) return;
    int beg = rowoff[d];
    int end = (d + 1 < n) ? rowoff[d + 1] : e;
    float acc = 0.f;
    for (int p = beg; p < end; ++p) {
        int s = esrc[p];
        acc += feat[(size_t)s * 16 + j];
    }
    agg[(size_t)d * 16 + j] = acc;
}

// ---- h1s = relu(agg1*norm_dst + b1) * norm_src ----
__global__ __launch_bounds__(NT) void act_kernel(const float* __restrict__ agg,
                                                 const float* __restrict__ norm_dst,
                                                 const float* __restrict__ norm_src,
                                                 const float* __restrict__ b1,
                                                 float* __restrict__ h1s, int n) {
    int t = blockIdx.x * NT + threadIdx.x;
    if (t >= n * 4) return;
    int i = t >> 2, q = t & 3;
    float nd = norm_dst[i], ns = norm_src[i];
    float4 a = *(const float4*)&agg[(size_t)i * 16 + q * 4];
    float4 bb = *(const float4*)&b1[q * 4];
    float4 r;
    r.x = fmaxf(a.x * nd + bb.x, 0.f) * ns;
    r.y = fmaxf(a.y * nd + bb.y, 0.f) * ns;
    r.z = fmaxf(a.z * nd + bb.z, 0.f) * ns;
    r.w = fmaxf(a.w * nd + bb.w, 0.f) * ns;
    *(float4*)&h1s[(size_t)i * 16 + q * 4] = r;
}

// ---- out[i][j] = (agg2[i] @ W2)[j] * norm_dst[i] + b2[j] ----
__global__ __launch_bounds__(NT) void final_kernel(const float* __restrict__ agg,
                                                   const float* __restrict__ W2,
                                                   const float* __restrict__ b2,
                                                   const float* __restrict__ norm_dst,
                                                   float* __restrict__ out, int n) {
    __shared__ float sW[16 * 64];
    __shared__ float sA[4][16];
    int tid = threadIdx.x;
    *(float4*)&sW[tid * 4] = *(const float4*)&W2[tid * 4];
    int i0 = blockIdx.x * 4;
    if (tid < 64) {
        int r = tid >> 4, k = tid & 15;
        int gi = i0 + r;
        sA[r][k] = (gi < n) ? agg[(size_t)gi * 16 + k] : 0.f;
    }
    __syncthreads();
    int r = tid >> 6, j = tid & 63;
    int gi = i0 + r;
    if (gi >= n) return;
    float acc = 0.f;
#pragma unroll
    for (int k = 0; k < 16; k++) acc += sA[r][k] * sW[k * 64 + j];
    out[(size_t)gi * 64 + j] = acc * norm_dst[gi] + b2[j];
}

// ---------------------------------------------------------------------------
// Launch
// ---------------------------------------------------------------------------
extern "C" void kernel_launch(void* const* d_in, const int* in_sizes, int n_in,
                              void* d_out, int out_size, void* d_ws, size_t ws_size,
                              hipStream_t stream) {
    const float* x  = (const float*)d_in[0];
    const float* W1 = (const float*)d_in[1];
    const float* b1 = (const float*)d_in[2];
    const float* W2 = (const float*)d_in[3];
    const float* b2 = (const float*)d_in[4];
    const int* src  = (const int*)d_in[5];
    const int* dst  = (const int*)d_in[6];

    int n = in_sizes[0] / 512;   // 100000
    int e = in_sizes[5];         // 3200000
    float* out = (float*)d_out;

    int nbkt = (n + 255) >> 8;   // 391

    char* ws = (char*)d_ws;
    size_t off = 0;
    auto alloc = [&](size_t bytes) { size_t o = off; off = (off + bytes + 255) & ~(size_t)255; return o; };
    int*   cntD  = (int*)(ws + alloc(MAXBKT * 4));
    int*   cntS  = (int*)(ws + alloc(MAXBKT * 4));
    size_t zero_end = off;                       // memset region [0, zero_end)
    int*   bkoD  = (int*)(ws + alloc((MAXBKT + 1) * 4));
    int*   bkoS  = (int*)(ws + alloc((MAXBKT + 1) * 4));
    int*   gcurD = (int*)(ws + alloc(MAXBKT * 4));
    int*   gcurS = (int*)(ws + alloc(MAXBKT * 4));
    float* norm_src = (float*)(ws + alloc((size_t)n * 4));
    float* norm_dst = (float*)(ws + alloc((size_t)n * 4));
    int*   rowoff   = (int*)(ws + alloc((size_t)n * 4));
    unsigned int*  ebinD  = (unsigned int*)(ws + alloc((size_t)e * 4));
    unsigned char* ebinS8 = (unsigned char*)(ws + alloc((size_t)e));
    int*   esrc   = (int*)(ws + alloc((size_t)e * 4));
    float* bufA   = (float*)(ws + alloc((size_t)n * 16 * 4));
    float* bufAgg = (float*)(ws + alloc((size_t)n * 16 * 4));
    float* partial = (float*)(ws + alloc((size_t)KS * n * 16 * 4));
    if (off > ws_size) return;

    int ebb = (e + EPB - 1) / EPB;    // 391 blocks
    int nb4 = ((n * 4) + NT - 1) / NT;
    int nrb = (n + GROWS - 1) / GROWS;  // 391 row-blocks

    hipMemsetAsync(ws, 0, zero_end, stream);

    bucket_count  <<<ebb, NT, 0, stream>>>(src, dst, cntD, cntS, e, nbkt);
    bucket_scan   <<<1, 512, 0, stream>>>(cntD, cntS, bkoD, bkoS, gcurD, gcurS, e, nbkt);
    bucket_scatter<<<ebb, NT, 0, stream>>>(src, dst, gcurD, gcurS, ebinD, ebinS8, e, nbkt);
    src_degree    <<<nbkt, NT, 0, stream>>>(ebinS8, bkoS, norm_src, n);
    gemm1_partial <<<nrb * KS, NT, 0, stream>>>(x, W1, partial, n, nrb);
    reduce_kernel <<<nb4, NT, 0, stream>>>(partial, norm_src, bufA, n);
    dst_fill      <<<nbkt, NT, 0, stream>>>(ebinD, bkoD, rowoff, norm_dst, esrc, n);
    aggregate16   <<<(n + 15) / 16, NT, 0, stream>>>(bufA, rowoff, esrc, bufAgg, n, e);
    act_kernel    <<<nb4, NT, 0, stream>>>(bufAgg, norm_dst, norm_src, b1, bufA, n);
    aggregate16   <<<(n + 15) / 16, NT, 0, stream>>>(bufA, rowoff, esrc, bufAgg, n, e);
    final_kernel  <<<(n + 3) / 4, NT, 0, stream>>>(bufAgg, W2, b2, norm_dst, out, n);
}

// Round 4
// 325.963 us; speedup vs baseline: 2.6061x; 1.2697x over previous
//
#include <hip/hip_runtime.h>

#define NT 256
#define EPB 4096       // edges per block for bucket passes
#define MAXBKT 512     // static LDS sizing; nbkt = ceil(n/256) = 391 for n=100000

typedef __bf16 bf16x8 __attribute__((ext_vector_type(8)));
typedef float f32x4 __attribute__((ext_vector_type(4)));

__device__ __forceinline__ unsigned short f2bf(float f) {
    unsigned int u = __float_as_uint(f);
    unsigned int r = u + 0x7FFFu + ((u >> 16) & 1u);   // RNE
    return (unsigned short)(r >> 16);
}
__device__ __forceinline__ float bf2f(unsigned short h) {
    return __uint_as_float(((unsigned int)h) << 16);
}

// ---------------------------------------------------------------------------
// Pass A: histogram edges into dst-buckets and src-buckets (bucket = id >> 8)
// ---------------------------------------------------------------------------
__global__ __launch_bounds__(NT) void bucket_count(const int* __restrict__ src,
                                                   const int* __restrict__ dst,
                                                   int* __restrict__ cntD,
                                                   int* __restrict__ cntS, int e, int nbkt) {
    __shared__ int hD[MAXBKT], hS[MAXBKT];
    int tid = threadIdx.x;
    for (int i = tid; i < nbkt; i += NT) { hD[i] = 0; hS[i] = 0; }
    __syncthreads();
    int p0 = blockIdx.x * EPB;
    int pend = min(p0 + EPB, e);
    for (int p = p0 + tid; p < pend; p += NT) {
        atomicAdd(&hD[dst[p] >> 8], 1);
        atomicAdd(&hS[src[p] >> 8], 1);
    }
    __syncthreads();
    for (int i = tid; i < nbkt; i += NT) {
        if (hD[i]) atomicAdd(&cntD[i], hD[i]);
        if (hS[i]) atomicAdd(&cntS[i], hS[i]);
    }
}

// ---------------------------------------------------------------------------
// Pass B: exclusive scan of bucket counts (nbkt <= 512, one block)
// ---------------------------------------------------------------------------
__global__ __launch_bounds__(512) void bucket_scan(const int* __restrict__ cntD,
                                                   const int* __restrict__ cntS,
                                                   int* __restrict__ bkoD,
                                                   int* __restrict__ bkoS,
                                                   int* __restrict__ gcurD,
                                                   int* __restrict__ gcurS, int e, int nbkt) {
    __shared__ int tD[512], tS[512];
    int tid = threadIdx.x;
    int vD = (tid < nbkt) ? cntD[tid] : 0;
    int vS = (tid < nbkt) ? cntS[tid] : 0;
    int valD = vD, valS = vS;
    tD[tid] = valD; tS[tid] = valS;
    __syncthreads();
    for (int off = 1; off < 512; off <<= 1) {
        int aD = (tid >= off) ? tD[tid - off] : 0;
        int aS = (tid >= off) ? tS[tid - off] : 0;
        __syncthreads();
        valD += aD; valS += aS;
        tD[tid] = valD; tS[tid] = valS;
        __syncthreads();
    }
    if (tid < nbkt) {
        int oD = valD - vD, oS = valS - vS;
        bkoD[tid] = oD; bkoS[tid] = oS;
        gcurD[tid] = oD; gcurS[tid] = oS;
    }
    if (tid == 0) { bkoD[nbkt] = e; bkoS[nbkt] = e; }
}

// ---------------------------------------------------------------------------
// Pass C: scatter edges into bucket regions (block-local LDS bucketing)
//   ebinD[slot] = src | (dst&255)<<17   (src < 2^17, n=100000)
//   ebinS8[slot] = src & 255            (bucket implied by slot position)
// ---------------------------------------------------------------------------
__global__ __launch_bounds__(NT) void bucket_scatter(const int* __restrict__ src,
                                                     const int* __restrict__ dst,
                                                     int* __restrict__ gcurD,
                                                     int* __restrict__ gcurS,
                                                     unsigned int* __restrict__ ebinD,
                                                     unsigned char* __restrict__ ebinS8,
                                                     int e, int nbkt) {
    __shared__ int hD[MAXBKT], hS[MAXBKT];
    __shared__ int cD[MAXBKT], cS[MAXBKT];
    int tid = threadIdx.x;
    for (int i = tid; i < nbkt; i += NT) { hD[i] = 0; hS[i] = 0; }
    __syncthreads();
    int p0 = blockIdx.x * EPB;
    int pend = min(p0 + EPB, e);
    for (int p = p0 + tid; p < pend; p += NT) {
        atomicAdd(&hD[dst[p] >> 8], 1);
        atomicAdd(&hS[src[p] >> 8], 1);
    }
    __syncthreads();
    for (int i = tid; i < nbkt; i += NT) {
        cD[i] = hD[i] ? atomicAdd(&gcurD[i], hD[i]) : 0;
        cS[i] = hS[i] ? atomicAdd(&gcurS[i], hS[i]) : 0;
    }
    __syncthreads();
    for (int p = p0 + tid; p < pend; p += NT) {
        int s = src[p], d = dst[p];
        int slotD = atomicAdd(&cD[d >> 8], 1);
        ebinD[slotD] = (unsigned int)s | ((unsigned int)(d & 255) << 17);
        int slotS = atomicAdd(&cS[s >> 8], 1);
        ebinS8[slotS] = (unsigned char)(s & 255);
    }
}

// ---------------------------------------------------------------------------
// Pass D_s: per-bucket out-degree histogram -> norm_src
// ---------------------------------------------------------------------------
__global__ __launch_bounds__(NT) void src_degree(const unsigned char* __restrict__ ebinS8,
                                                 const int* __restrict__ bkoS,
                                                 float* __restrict__ norm_src, int n) {
    __shared__ int cnt[256];
    int b = blockIdx.x, tid = threadIdx.x;
    cnt[tid] = 0;
    __syncthreads();
    int p0 = bkoS[b], p1 = bkoS[b + 1];
    for (int p = p0 + tid; p < p1; p += NT) atomicAdd(&cnt[ebinS8[p]], 1);
    __syncthreads();
    int node = (b << 8) + tid;
    if (node < n) norm_src[node] = rsqrtf((float)max(cnt[tid], 1));
}

// ---------------------------------------------------------------------------
// Pass D_d: per-bucket in-degree histogram + LDS scan -> rowoff, norm_dst,
//           then fill esrc within the bucket's contiguous edge region
// ---------------------------------------------------------------------------
__global__ __launch_bounds__(NT) void dst_fill(const unsigned int* __restrict__ ebinD,
                                               const int* __restrict__ bkoD,
                                               int* __restrict__ rowoff,
                                               float* __restrict__ norm_dst,
                                               int* __restrict__ esrc, int n) {
    __shared__ int cnt[256], cur[256], tmp[256];
    int b = blockIdx.x, tid = threadIdx.x;
    cnt[tid] = 0;
    __syncthreads();
    int p0 = bkoD[b], p1 = bkoD[b + 1];
    for (int p = p0 + tid; p < p1; p += NT) atomicAdd(&cnt[ebinD[p] >> 17], 1);
    __syncthreads();
    int v = cnt[tid];
    int val = v;
    tmp[tid] = val;
    __syncthreads();
    for (int off = 1; off < 256; off <<= 1) {
        int a = (tid >= off) ? tmp[tid - off] : 0;
        __syncthreads();
        val += a;
        tmp[tid] = val;
        __syncthreads();
    }
    int excl = val - v;
    int node = (b << 8) + tid;
    if (node < n) {
        rowoff[node] = p0 + excl;
        norm_dst[node] = rsqrtf((float)max(v, 1));
    }
    cur[tid] = p0 + excl;
    __syncthreads();
    for (int p = p0 + tid; p < p1; p += NT) {
        unsigned int w = ebinD[p];
        int pos = atomicAdd(&cur[w >> 17], 1);
        esrc[pos] = (int)(w & 0x1FFFFu);
    }
}

// ---------------------------------------------------------------------------
// W1 prep: W1[512][16] f32 -> W1T hi/lo bf16 [16][512] (B^T fragment layout)
// ---------------------------------------------------------------------------
__global__ __launch_bounds__(NT) void w1t_prep(const float* __restrict__ W1,
                                               unsigned short* __restrict__ w1t_hi,
                                               unsigned short* __restrict__ w1t_lo) {
    int t = blockIdx.x * NT + threadIdx.x;
    if (t >= 512 * 16) return;
    int k = t >> 4, c = t & 15;
    float f = W1[k * 16 + c];
    unsigned short h = f2bf(f);
    w1t_hi[c * 512 + k] = h;
    w1t_lo[c * 512 + k] = f2bf(f - bf2f(h));
}

// ---------------------------------------------------------------------------
// GEMM1 via split-precision bf16 MFMA:
//   y1[i][j] = (x[i] @ W1)[j] * norm_src[i],  x = hi + lo (bf16 pair)
//   64 rows/block (4 waves x 16-row MFMA tiles), K staged in 64-wide chunks
// ---------------------------------------------------------------------------
#define GR 64
__global__ __launch_bounds__(NT) void gemm1_mfma(const float* __restrict__ x,
                                                 const unsigned short* __restrict__ w1t_hi,
                                                 const unsigned short* __restrict__ w1t_lo,
                                                 const float* __restrict__ norm_src,
                                                 float* __restrict__ y1, int n) {
    __shared__ __attribute__((aligned(16))) unsigned short sh_hi[GR][72];
    __shared__ __attribute__((aligned(16))) unsigned short sh_lo[GR][72];
    int tid = threadIdx.x;
    int w = tid >> 6, l = tid & 63;
    int row0 = blockIdx.x * GR;

    f32x4 acc = {0.f, 0.f, 0.f, 0.f};
    int col = l & 15;               // B col / D col
    int kq = (l >> 4) * 8;          // k offset within a 32-k step
    int arow = w * 16 + (l & 15);   // A row within block tile

    for (int kc = 0; kc < 512; kc += 64) {
        __syncthreads();
#pragma unroll
        for (int i = 0; i < 4; i++) {
            int idx = tid + i * NT;        // 0..1023
            int r = idx >> 4;              // 0..63
            int c4 = idx & 15;             // 0..15 (float4 col)
            int grow = row0 + r;
            float4 v = make_float4(0.f, 0.f, 0.f, 0.f);
            if (grow < n) v = *(const float4*)&x[(size_t)grow * 512 + kc + c4 * 4];
            ushort4 hv, lv;
            hv.x = f2bf(v.x); lv.x = f2bf(v.x - bf2f(hv.x));
            hv.y = f2bf(v.y); lv.y = f2bf(v.y - bf2f(hv.y));
            hv.z = f2bf(v.z); lv.z = f2bf(v.z - bf2f(hv.z));
            hv.w = f2bf(v.w); lv.w = f2bf(v.w - bf2f(hv.w));
            *(ushort4*)&sh_hi[r][c4 * 4] = hv;
            *(ushort4*)&sh_lo[r][c4 * 4] = lv;
        }
        __syncthreads();
#pragma unroll
        for (int ks = 0; ks < 2; ks++) {
            int klocal = ks * 32 + kq;
            bf16x8 a_hi = *(const bf16x8*)&sh_hi[arow][klocal];
            bf16x8 a_lo = *(const bf16x8*)&sh_lo[arow][klocal];
            int kglob = kc + klocal;
            bf16x8 b_hi = *(const bf16x8*)&w1t_hi[col * 512 + kglob];
            bf16x8 b_lo = *(const bf16x8*)&w1t_lo[col * 512 + kglob];
            acc = __builtin_amdgcn_mfma_f32_16x16x32_bf16(a_hi, b_hi, acc, 0, 0, 0);
            acc = __builtin_amdgcn_mfma_f32_16x16x32_bf16(a_lo, b_hi, acc, 0, 0, 0);
            acc = __builtin_amdgcn_mfma_f32_16x16x32_bf16(a_hi, b_lo, acc, 0, 0, 0);
        }
    }

    int rbase = (l >> 4) * 4;       // D row = (lane>>4)*4 + reg
#pragma unroll
    for (int r = 0; r < 4; r++) {
        int grow = row0 + w * 16 + rbase + r;
        if (grow < n) y1[(size_t)grow * 16 + col] = acc[r] * norm_src[grow];
    }
}

// ---------------------------------------------------------------------------
// Aggregate layer 1 + fused activation: h1s[d] = relu(sum*nd + b1) * ns
// ---------------------------------------------------------------------------
__global__ __launch_bounds__(NT) void aggregate_act(const float* __restrict__ feat,
                                                    const int* __restrict__ rowoff,
                                                    const int* __restrict__ esrc,
                                                    const float* __restrict__ norm_dst,
                                                    const float* __restrict__ norm_src,
                                                    const float* __restrict__ b1,
                                                    float* __restrict__ h1s, int n, int e) {
    int tid = threadIdx.x;
    int d = blockIdx.x * 16 + (tid >> 4);
    int j = tid & 15;
    if (d >= n) return;
    int beg = rowoff[d];
    int end = (d + 1 < n) ? rowoff[d + 1] : e;
    float acc0 = 0.f, acc1 = 0.f;
    int p = beg;
    for (; p + 1 < end; p += 2) {
        int s0 = esrc[p], s1 = esrc[p + 1];
        acc0 += feat[(size_t)s0 * 16 + j];
        acc1 += feat[(size_t)s1 * 16 + j];
    }
    if (p < end) acc0 += feat[(size_t)esrc[p] * 16 + j];
    float acc = acc0 + acc1;
    float v = fmaxf(acc * norm_dst[d] + b1[j], 0.f) * norm_src[d];
    h1s[(size_t)d * 16 + j] = v;
}

// ---------------------------------------------------------------------------
// Aggregate layer 2 + fused final GEMM: out[d][:] = (sum @ W2)*nd + b2
// ---------------------------------------------------------------------------
__global__ __launch_bounds__(NT) void aggregate_final(const float* __restrict__ feat,
                                                      const int* __restrict__ rowoff,
                                                      const int* __restrict__ esrc,
                                                      const float* __restrict__ norm_dst,
                                                      const float* __restrict__ W2,
                                                      const float* __restrict__ b2,
                                                      float* __restrict__ out, int n, int e) {
    __shared__ float sW[16 * 64];
    int tid = threadIdx.x;
    *(float4*)&sW[tid * 4] = *(const float4*)&W2[tid * 4];
    __syncthreads();
    int d = blockIdx.x * 16 + (tid >> 4);
    int j = tid & 15;
    if (d >= n) return;
    int beg = rowoff[d];
    int end = (d + 1 < n) ? rowoff[d + 1] : e;
    float acc0 = 0.f, acc1 = 0.f;
    int p = beg;
    for (; p + 1 < end; p += 2) {
        int s0 = esrc[p], s1 = esrc[p + 1];
        acc0 += feat[(size_t)s0 * 16 + j];
        acc1 += feat[(size_t)s1 * 16 + j];
    }
    if (p < end) acc0 += feat[(size_t)esrc[p] * 16 + j];
    float acc = acc0 + acc1;
    float nd = norm_dst[d];
    float o0 = 0.f, o1 = 0.f, o2 = 0.f, o3 = 0.f;
#pragma unroll
    for (int k = 0; k < 16; k++) {
        float ak = __shfl(acc, k, 16);
        o0 += ak * sW[k * 64 + j];
        o1 += ak * sW[k * 64 + j + 16];
        o2 += ak * sW[k * 64 + j + 32];
        o3 += ak * sW[k * 64 + j + 48];
    }
    size_t ob = (size_t)d * 64;
    out[ob + j]      = o0 * nd + b2[j];
    out[ob + j + 16] = o1 * nd + b2[j + 16];
    out[ob + j + 32] = o2 * nd + b2[j + 32];
    out[ob + j + 48] = o3 * nd + b2[j + 48];
}

// ---------------------------------------------------------------------------
// Launch
// ---------------------------------------------------------------------------
extern "C" void kernel_launch(void* const* d_in, const int* in_sizes, int n_in,
                              void* d_out, int out_size, void* d_ws, size_t ws_size,
                              hipStream_t stream) {
    const float* x  = (const float*)d_in[0];
    const float* W1 = (const float*)d_in[1];
    const float* b1 = (const float*)d_in[2];
    const float* W2 = (const float*)d_in[3];
    const float* b2 = (const float*)d_in[4];
    const int* src  = (const int*)d_in[5];
    const int* dst  = (const int*)d_in[6];

    int n = in_sizes[0] / 512;   // 100000
    int e = in_sizes[5];         // 3200000
    float* out = (float*)d_out;

    int nbkt = (n + 255) >> 8;   // 391

    char* ws = (char*)d_ws;
    size_t off = 0;
    auto alloc = [&](size_t bytes) { size_t o = off; off = (off + bytes + 255) & ~(size_t)255; return o; };
    int*   cntD  = (int*)(ws + alloc(MAXBKT * 4));
    int*   cntS  = (int*)(ws + alloc(MAXBKT * 4));
    size_t zero_end = off;                       // memset region [0, zero_end)
    int*   bkoD  = (int*)(ws + alloc((MAXBKT + 1) * 4));
    int*   bkoS  = (int*)(ws + alloc((MAXBKT + 1) * 4));
    int*   gcurD = (int*)(ws + alloc(MAXBKT * 4));
    int*   gcurS = (int*)(ws + alloc(MAXBKT * 4));
    float* norm_src = (float*)(ws + alloc((size_t)n * 4));
    float* norm_dst = (float*)(ws + alloc((size_t)n * 4));
    int*   rowoff   = (int*)(ws + alloc((size_t)n * 4));
    unsigned int*  ebinD  = (unsigned int*)(ws + alloc((size_t)e * 4));
    unsigned char* ebinS8 = (unsigned char*)(ws + alloc((size_t)e));
    int*   esrc   = (int*)(ws + alloc((size_t)e * 4));
    float* bufA   = (float*)(ws + alloc((size_t)n * 16 * 4));   // y1
    float* bufB   = (float*)(ws + alloc((size_t)n * 16 * 4));   // h1s
    unsigned short* w1t_hi = (unsigned short*)(ws + alloc(16 * 512 * 2));
    unsigned short* w1t_lo = (unsigned short*)(ws + alloc(16 * 512 * 2));
    if (off > ws_size) return;

    int ebb = (e + EPB - 1) / EPB;      // 782 blocks
    int grb = (n + GR - 1) / GR;        // 1563 blocks

    hipMemsetAsync(ws, 0, zero_end, stream);

    bucket_count   <<<ebb, NT, 0, stream>>>(src, dst, cntD, cntS, e, nbkt);
    bucket_scan    <<<1, 512, 0, stream>>>(cntD, cntS, bkoD, bkoS, gcurD, gcurS, e, nbkt);
    bucket_scatter <<<ebb, NT, 0, stream>>>(src, dst, gcurD, gcurS, ebinD, ebinS8, e, nbkt);
    src_degree     <<<nbkt, NT, 0, stream>>>(ebinS8, bkoS, norm_src, n);
    w1t_prep       <<<32, NT, 0, stream>>>(W1, w1t_hi, w1t_lo);
    gemm1_mfma     <<<grb, NT, 0, stream>>>(x, w1t_hi, w1t_lo, norm_src, bufA, n);
    dst_fill       <<<nbkt, NT, 0, stream>>>(ebinD, bkoD, rowoff, norm_dst, esrc, n);
    aggregate_act  <<<(n + 15) / 16, NT, 0, stream>>>(bufA, rowoff, esrc, norm_dst, norm_src, b1, bufB, n, e);
    aggregate_final<<<(n + 15) / 16, NT, 0, stream>>>(bufB, rowoff, esrc, norm_dst, W2, b2, out, n, e);
}